// Round 3
// baseline (82.252 us; speedup 1.0000x reference)
//
#include <hip/hip_runtime.h>

// WeightedStateLoss4: B=512, H=2048, D=64, fp32, scalar out.
// t[i]   = count_nonzero(targ[i, :, 1])
// w[i]   = 1 + 0.7 * (t/(H-1))^2.5
// idx[i] = clamp(t-1, 0, H-1)      (JAX take_along_axis clips)
// out    = mean_i( (pred[i,idx,0]-targ[i,idx,0])^2 * w[i] * D )
//
// Single fused kernel: per-(sample,chunk) count blocks + last-block finalize.
// Semaphore = monotonic counter mod gridSize -> works from any initial ws
// contents (harness poisons ws to 0xAA and never re-poisons between replays).

#define BB 512
#define HH 2048
#define DD 64
#define CHUNKS 4
#define HPC (HH / CHUNKS)     // 512 rows per chunk; 256 threads x 2 rows
#define NBLK (BB * CHUNKS)    // 2048 blocks, power of two (wrap-safe mod)

__global__ __launch_bounds__(256) void wsl4_fused(
    const float* __restrict__ pred,
    const float* __restrict__ targ,
    int* __restrict__ ws,      // ws[0]=sem, ws[1..NBLK]=partial counts
    float* __restrict__ out)
{
    const int c   = blockIdx.x;
    const int i   = blockIdx.y;
    const int tid = threadIdx.x;

    // ---- phase 1: strided nonzero count of targ[i, chunk, 1] ----
    const float* p = targ + (size_t)i * HH * DD + (size_t)c * HPC * DD + 1;
    const float a = p[(size_t)tid * DD];
    const float b = p[((size_t)tid + 256) * DD];
    int cnt = (a != 0.0f ? 1 : 0) + (b != 0.0f ? 1 : 0);

#pragma unroll
    for (int off = 32; off > 0; off >>= 1)
        cnt += __shfl_down(cnt, off, 64);

    __shared__ int s[4];
    __shared__ int flag;
    if (tid == 0) flag = 0;
    if ((tid & 63) == 0) s[tid >> 6] = cnt;
    __syncthreads();

    if (tid == 0) {
        const int total = s[0] + s[1] + s[2] + s[3];
        // agent-scope store: visible past this XCD's L2
        __hip_atomic_store(&ws[1 + i * CHUNKS + c], total,
                           __ATOMIC_RELAXED, __HIP_MEMORY_SCOPE_AGENT);
        const unsigned old = __hip_atomic_fetch_add(
            (unsigned*)&ws[0], 1u, __ATOMIC_ACQ_REL, __HIP_MEMORY_SCOPE_AGENT);
        if (((old + 1u) & (unsigned)(NBLK - 1)) == 0u) flag = 1;
    }
    __syncthreads();
    if (flag == 0) return;

    // ---- phase 2: finalize (exactly one block per call) ----
    float acc = 0.0f;
#pragma unroll
    for (int k = 0; k < 2; ++k) {
        const int smp = tid + k * 256;        // sample 0..511
        int t = 0;
#pragma unroll
        for (int q = 0; q < CHUNKS; ++q)
            t += __hip_atomic_load(&ws[1 + smp * CHUNKS + q],
                                   __ATOMIC_RELAXED, __HIP_MEMORY_SCOPE_AGENT);

        const float ratio = (float)t * (1.0f / (float)(HH - 1));
        const float w = 1.0f + 0.7f * powf(ratio, 2.5f);

        int idx = t - 1;
        idx = idx < 0 ? 0 : (idx > HH - 1 ? HH - 1 : idx);

        const size_t base = ((size_t)smp * HH + (size_t)idx) * DD;  // ch 0
        const float d = pred[base] - targ[base];
        acc += d * d * w;
    }
    acc *= (float)DD / (float)BB;

#pragma unroll
    for (int off = 32; off > 0; off >>= 1)
        acc += __shfl_down(acc, off, 64);

    __shared__ float sf[4];
    if ((tid & 63) == 0) sf[tid >> 6] = acc;
    __syncthreads();
    if (tid == 0) out[0] = sf[0] + sf[1] + sf[2] + sf[3];
}

extern "C" void kernel_launch(void* const* d_in, const int* in_sizes, int n_in,
                              void* d_out, int out_size, void* d_ws, size_t ws_size,
                              hipStream_t stream)
{
    const float* pred = (const float*)d_in[0];
    const float* targ = (const float*)d_in[1];

    dim3 grid(CHUNKS, BB);
    wsl4_fused<<<grid, 256, 0, stream>>>(pred, targ, (int*)d_ws, (float*)d_out);
}

// Round 4
// 29.478 us; speedup vs baseline: 2.7903x; 2.7903x over previous
//
#include <hip/hip_runtime.h>

// WeightedStateLoss4: B=512, H=2048, D=64, fp32, scalar out.
// t[i]   = count_nonzero(targ[i, :, 1])
// w[i]   = 1 + 0.7 * (t/(H-1))^2.5
// idx[i] = clamp(t-1, 0, H-1)      (JAX take_along_axis clips)
// out    = mean_i( (pred[i,idx,0]-targ[i,idx,0])^2 * w[i] * D )
//
// Structure: one block per sample does count + per-sample weighted loss
// (gathers hidden under other blocks' count traffic); a trivial one-wave
// kernel reduces the 512 per-sample losses. No atomics, no memset:
// ws slots are fully overwritten every call.

#define BB 512
#define HH 2048
#define DD 64

// Kernel A: per-sample count + weighted per-sample loss -> sloss[i].
// 1024 threads x 2 strided loads = 2048 rows. 512 blocks -> 2 blocks/CU,
// 32 waves/CU (full occupancy), 64 wave-loads in flight per CU.
__global__ __launch_bounds__(1024) void wsl4_sample(
    const float* __restrict__ pred,
    const float* __restrict__ targ,
    float* __restrict__ sloss)
{
    const int i   = blockIdx.x;
    const int tid = threadIdx.x;

    const float* t1 = targ + (size_t)i * HH * DD + 1;   // channel 1
    const float a = t1[(size_t)tid * DD];
    const float b = t1[((size_t)tid + 1024) * DD];
    int cnt = (a != 0.0f ? 1 : 0) + (b != 0.0f ? 1 : 0);

#pragma unroll
    for (int off = 32; off > 0; off >>= 1)
        cnt += __shfl_down(cnt, off, 64);

    __shared__ int s[16];
    if ((tid & 63) == 0) s[tid >> 6] = cnt;
    __syncthreads();

    if (tid == 0) {
        int t = 0;
#pragma unroll
        for (int k = 0; k < 16; ++k) t += s[k];

        const float ratio = (float)t * (1.0f / (float)(HH - 1));
        const float w = 1.0f + 0.7f * powf(ratio, 2.5f);

        int idx = t - 1;
        idx = idx < 0 ? 0 : (idx > HH - 1 ? HH - 1 : idx);

        const size_t base = ((size_t)i * HH + (size_t)idx) * DD;  // ch 0
        const float d = pred[base] - targ[base];
        sloss[i] = d * d * w * ((float)DD / (float)BB);
    }
}

// Kernel B: one wave reduces 512 floats -> out[0].
__global__ __launch_bounds__(64) void wsl4_reduce(
    const float* __restrict__ sloss, float* __restrict__ out)
{
    const int tid = threadIdx.x;
    const float4* p4 = (const float4*)sloss;
    const float4 x = p4[tid * 2];
    const float4 y = p4[tid * 2 + 1];
    float v = (x.x + x.y) + (x.z + x.w) + (y.x + y.y) + (y.z + y.w);

#pragma unroll
    for (int off = 32; off > 0; off >>= 1)
        v += __shfl_down(v, off, 64);

    if (tid == 0) out[0] = v;
}

extern "C" void kernel_launch(void* const* d_in, const int* in_sizes, int n_in,
                              void* d_out, int out_size, void* d_ws, size_t ws_size,
                              hipStream_t stream)
{
    const float* pred = (const float*)d_in[0];
    const float* targ = (const float*)d_in[1];
    float* sloss = (float*)d_ws;          // 512 floats, overwritten each call

    wsl4_sample<<<BB, 1024, 0, stream>>>(pred, targ, sloss);
    wsl4_reduce<<<1, 64, 0, stream>>>(sloss, (float*)d_out);
}